// Round 1
// baseline (1032.948 us; speedup 1.0000x reference)
//
#include <hip/hip_runtime.h>
#include <hip/hip_bf16.h>
#include <math.h>

// B=2, S=2048, D=1024, H=16, hd=64. scaling=0.125, LN eps=1e-5.
typedef __bf16 bf16;
typedef __bf16 bf16x4 __attribute__((ext_vector_type(4)));
typedef __bf16 bf16x8 __attribute__((ext_vector_type(8)));
typedef float floatx4 __attribute__((ext_vector_type(4)));

#define MFMA16(a, b, c) __builtin_amdgcn_mfma_f32_16x16x32_bf16(a, b, c, 0, 0, 0)

// ---------------- K0: fp32 -> bf16 conversions --------------------------
// hidden (4M), Wq|Wk|Wv concat (3M), Wo (1M): 8M elements, 4 per thread.
__global__ __launch_bounds__(256) void k_convert(
    const float* __restrict__ hid, const float* __restrict__ wq,
    const float* __restrict__ wk, const float* __restrict__ wv,
    const float* __restrict__ wo,
    bf16* __restrict__ hidb, bf16* __restrict__ wqkvb, bf16* __restrict__ wob) {
  int g = blockIdx.x * 256 + threadIdx.x;
  int idx = g * 4;
  const float* src;
  bf16* dst;
  if (idx < 4194304) {
    src = hid + idx; dst = hidb + idx;
  } else if (idx < 7340032) {
    const float* w = (idx < 5242880) ? wq : (idx < 6291456) ? wk : wv;
    src = w + ((idx - 4194304) & 1048575);
    dst = wqkvb + (idx - 4194304);
  } else {
    src = wo + (idx - 7340032); dst = wob + (idx - 7340032);
  }
  float4 v = *(const float4*)src;
  bf16x4 o;
  o[0] = (bf16)v.x; o[1] = (bf16)v.y; o[2] = (bf16)v.z; o[3] = (bf16)v.w;
  *(bf16x4*)dst = o;
}

// ---------------- K1: fused QKV GEMM ------------------------------------
// C[m,n] = sum_k A[m,k]*Bt[n,k];  M=4096, N=3072, K=1024.
// 128x128 tile, 4 waves each 64x64, 16x16x32 bf16 MFMA, BK=64.
// Epilogue: +bias, q*=0.125, scatter to Q[bh,s,d], K[bh,s,d], V[bh,d,s].
__global__ __launch_bounds__(256) void k_qkv_gemm(
    const bf16* __restrict__ A, const bf16* __restrict__ Bt,
    const float* __restrict__ bq, const float* __restrict__ bk,
    const float* __restrict__ bv,
    bf16* __restrict__ Qb, bf16* __restrict__ Kb, bf16* __restrict__ Vb) {
  __shared__ __align__(16) bf16 Al[128 * 64];
  __shared__ __align__(16) bf16 Bl[128 * 64];
  int tid = threadIdx.x;
  int wave = tid >> 6, L = tid & 63, quad = L >> 4, ln = L & 15;
  int m0 = blockIdx.y * 128, n0 = blockIdx.x * 128;
  int wm = (wave >> 1) * 64, wn = (wave & 1) * 64;

  floatx4 zz = {0.f, 0.f, 0.f, 0.f};
  floatx4 acc[4][4];
#pragma unroll
  for (int i = 0; i < 4; i++)
#pragma unroll
    for (int j = 0; j < 4; j++) acc[i][j] = zz;

  for (int kk = 0; kk < 1024; kk += 64) {
    uint4 ar[4], br[4];
#pragma unroll
    for (int u = 0; u < 4; u++) {
      int ch = tid + u * 256;
      int r = ch >> 3, c8 = ch & 7;
      ar[u] = *(const uint4*)&A[(size_t)(m0 + r) * 1024 + kk + c8 * 8];
      br[u] = *(const uint4*)&Bt[(size_t)(n0 + r) * 1024 + kk + c8 * 8];
    }
    __syncthreads();
#pragma unroll
    for (int u = 0; u < 4; u++) {
      int ch = tid + u * 256;
      int r = ch >> 3, c8 = ch & 7;
      *(uint4*)&Al[r * 64 + c8 * 8] = ar[u];
      *(uint4*)&Bl[r * 64 + c8 * 8] = br[u];
    }
    __syncthreads();
#pragma unroll
    for (int t = 0; t < 64; t += 32) {
      bf16x8 af[4], bfr[4];
#pragma unroll
      for (int i = 0; i < 4; i++)
        af[i] = *(const bf16x8*)&Al[(wm + i * 16 + ln) * 64 + t + quad * 8];
#pragma unroll
      for (int j = 0; j < 4; j++)
        bfr[j] = *(const bf16x8*)&Bl[(wn + j * 16 + ln) * 64 + t + quad * 8];
#pragma unroll
      for (int i = 0; i < 4; i++)
#pragma unroll
        for (int j = 0; j < 4; j++) acc[i][j] = MFMA16(af[i], bfr[j], acc[i][j]);
    }
  }
#pragma unroll
  for (int i = 0; i < 4; i++) {
    int mbase = m0 + wm + i * 16 + quad * 4;
#pragma unroll
    for (int j = 0; j < 4; j++) {
      int n = n0 + wn + j * 16 + ln;
      int which = n >> 10, nn = n & 1023;
      float bias = (which == 0) ? bq[nn] : (which == 1) ? bk[nn] : bv[nn];
      int h = nn >> 6, d = nn & 63;
#pragma unroll
      for (int r = 0; r < 4; r++) {
        int mm = mbase + r;
        int b = mm >> 11, s = mm & 2047;
        int bh = b * 16 + h;
        float v = acc[i][j][r] + bias;
        if (which == 0)
          Qb[(size_t)bh * 131072 + s * 64 + d] = (bf16)(v * 0.125f);
        else if (which == 1)
          Kb[(size_t)bh * 131072 + s * 64 + d] = (bf16)v;
        else
          Vb[(size_t)bh * 131072 + (size_t)d * 2048 + s] = (bf16)v;
      }
    }
  }
}

// ---------------- K2: flash attention + extra_attn + mask ----------------
// Block: 64 q-rows, 4 waves x 16 q-rows. K-tile = 64 keys. Q,K: [bh,s,64];
// V transposed: [bh,64,2048]. extra: [bh,2048,2048] fp32; mask: [b,2048,2048].
__global__ __launch_bounds__(256) void k_attn(
    const bf16* __restrict__ Qb, const bf16* __restrict__ Kb,
    const bf16* __restrict__ Vb, const float* __restrict__ extra,
    const float* __restrict__ mask, bf16* __restrict__ ctx) {
  __shared__ __align__(16) bf16 Kl[64 * 64];
  __shared__ __align__(16) bf16 Vtl[64 * 64];
  __shared__ __align__(16) bf16 Pl[4][16 * 64];
  int tid = threadIdx.x;
  int wave = tid >> 6, L = tid & 63, quad = L >> 4, ln = L & 15;
  int bh = blockIdx.y, b = bh >> 4, h = bh & 15;
  int q0 = blockIdx.x * 64;
  int qrow = q0 + wave * 16;

  bf16x8 qf[2];
  qf[0] = *(const bf16x8*)&Qb[(size_t)bh * 131072 + (qrow + ln) * 64 + quad * 8];
  qf[1] = *(const bf16x8*)&Qb[(size_t)bh * 131072 + (qrow + ln) * 64 + 32 + quad * 8];

  float m_run[4], l_run[4];
  floatx4 zz = {0.f, 0.f, 0.f, 0.f};
  floatx4 Oacc[4];
#pragma unroll
  for (int r = 0; r < 4; r++) { m_run[r] = -INFINITY; l_run[r] = 0.f; }
#pragma unroll
  for (int dd = 0; dd < 4; dd++) Oacc[dd] = zz;

  const size_t ebase = (size_t)bh * 2048 * 2048;
  const size_t mbase = (size_t)b * 2048 * 2048;

  for (int k0 = 0; k0 < 2048; k0 += 64) {
    __syncthreads();  // all waves done reading Kl/Vtl from previous tile
#pragma unroll
    for (int u = 0; u < 2; u++) {
      int ch = tid + u * 256;
      int row = ch >> 3, c8 = ch & 7;
      *(uint4*)&Kl[row * 64 + c8 * 8] =
          *(const uint4*)&Kb[(size_t)bh * 131072 + (k0 + row) * 64 + c8 * 8];
      *(uint4*)&Vtl[row * 64 + c8 * 8] =
          *(const uint4*)&Vb[(size_t)bh * 131072 + (size_t)row * 2048 + k0 + c8 * 8];
    }
    __syncthreads();

    // scores: 16q x 64k per wave
    floatx4 sc[4];
#pragma unroll
    for (int kb = 0; kb < 4; kb++) {
      bf16x8 kf0 = *(const bf16x8*)&Kl[(kb * 16 + ln) * 64 + quad * 8];
      bf16x8 kf1 = *(const bf16x8*)&Kl[(kb * 16 + ln) * 64 + 32 + quad * 8];
      floatx4 z = zz;
      z = MFMA16(qf[0], kf0, z);
      z = MFMA16(qf[1], kf1, z);
      sc[kb] = z;
    }
    // + extra_attn + mask (fp32)
#pragma unroll
    for (int kb = 0; kb < 4; kb++) {
      int col = k0 + kb * 16 + ln;
#pragma unroll
      for (int r = 0; r < 4; r++) {
        int q = qrow + quad * 4 + r;
        sc[kb][r] += extra[ebase + (size_t)q * 2048 + col] +
                     mask[mbase + (size_t)q * 2048 + col];
      }
    }
    // online softmax; rows live in quad (lanes quad*16..+15 hold the cols)
#pragma unroll
    for (int r = 0; r < 4; r++) {
      float mloc = fmaxf(fmaxf(sc[0][r], sc[1][r]), fmaxf(sc[2][r], sc[3][r]));
      mloc = fmaxf(mloc, __shfl_xor(mloc, 1));
      mloc = fmaxf(mloc, __shfl_xor(mloc, 2));
      mloc = fmaxf(mloc, __shfl_xor(mloc, 4));
      mloc = fmaxf(mloc, __shfl_xor(mloc, 8));
      float m_new = fmaxf(m_run[r], mloc);
      float alpha = __expf(m_run[r] - m_new);
      m_run[r] = m_new;
      float rs = 0.f;
#pragma unroll
      for (int kb = 0; kb < 4; kb++) {
        float p = __expf(sc[kb][r] - m_new);
        sc[kb][r] = p;
        rs += p;
      }
      rs += __shfl_xor(rs, 1);
      rs += __shfl_xor(rs, 2);
      rs += __shfl_xor(rs, 4);
      rs += __shfl_xor(rs, 8);
      l_run[r] = l_run[r] * alpha + rs;
#pragma unroll
      for (int dd = 0; dd < 4; dd++) Oacc[dd][r] *= alpha;
      // P to LDS in C-layout positions (row=quad*4+r, col=kb*16+ln)
#pragma unroll
      for (int kb = 0; kb < 4; kb++)
        Pl[wave][(quad * 4 + r) * 64 + kb * 16 + ln] = (bf16)sc[kb][r];
    }
    // PV: P is A-operand (reads are per-wave, DS pipe is in-order)
    bf16x8 pf0 = *(const bf16x8*)&Pl[wave][ln * 64 + quad * 8];
    bf16x8 pf1 = *(const bf16x8*)&Pl[wave][ln * 64 + 32 + quad * 8];
#pragma unroll
    for (int dd = 0; dd < 4; dd++) {
      bf16x8 vf0 = *(const bf16x8*)&Vtl[(dd * 16 + ln) * 64 + quad * 8];
      bf16x8 vf1 = *(const bf16x8*)&Vtl[(dd * 16 + ln) * 64 + 32 + quad * 8];
      Oacc[dd] = MFMA16(pf0, vf0, Oacc[dd]);
      Oacc[dd] = MFMA16(pf1, vf1, Oacc[dd]);
    }
  }
  // write context [b, q, h*64+d] bf16
#pragma unroll
  for (int dd = 0; dd < 4; dd++) {
#pragma unroll
    for (int r = 0; r < 4; r++) {
      int q = qrow + quad * 4 + r;
      float v = Oacc[dd][r] / l_run[r];
      ctx[((size_t)(b * 2048 + q)) * 1024 + h * 64 + dd * 16 + ln] = (bf16)v;
    }
  }
}

// ---------------- K3a: output proj + bias + residual ---------------------
__global__ __launch_bounds__(256) void k_out_gemm(
    const bf16* __restrict__ A, const bf16* __restrict__ Bt,
    const float* __restrict__ bo, const float* __restrict__ hid,
    float* __restrict__ y) {
  __shared__ __align__(16) bf16 Al[128 * 64];
  __shared__ __align__(16) bf16 Bl[128 * 64];
  int tid = threadIdx.x;
  int wave = tid >> 6, L = tid & 63, quad = L >> 4, ln = L & 15;
  int m0 = blockIdx.y * 128, n0 = blockIdx.x * 128;
  int wm = (wave >> 1) * 64, wn = (wave & 1) * 64;

  floatx4 zz = {0.f, 0.f, 0.f, 0.f};
  floatx4 acc[4][4];
#pragma unroll
  for (int i = 0; i < 4; i++)
#pragma unroll
    for (int j = 0; j < 4; j++) acc[i][j] = zz;

  for (int kk = 0; kk < 1024; kk += 64) {
    uint4 ar[4], br[4];
#pragma unroll
    for (int u = 0; u < 4; u++) {
      int ch = tid + u * 256;
      int r = ch >> 3, c8 = ch & 7;
      ar[u] = *(const uint4*)&A[(size_t)(m0 + r) * 1024 + kk + c8 * 8];
      br[u] = *(const uint4*)&Bt[(size_t)(n0 + r) * 1024 + kk + c8 * 8];
    }
    __syncthreads();
#pragma unroll
    for (int u = 0; u < 4; u++) {
      int ch = tid + u * 256;
      int r = ch >> 3, c8 = ch & 7;
      *(uint4*)&Al[r * 64 + c8 * 8] = ar[u];
      *(uint4*)&Bl[r * 64 + c8 * 8] = br[u];
    }
    __syncthreads();
#pragma unroll
    for (int t = 0; t < 64; t += 32) {
      bf16x8 af[4], bfr[4];
#pragma unroll
      for (int i = 0; i < 4; i++)
        af[i] = *(const bf16x8*)&Al[(wm + i * 16 + ln) * 64 + t + quad * 8];
#pragma unroll
      for (int j = 0; j < 4; j++)
        bfr[j] = *(const bf16x8*)&Bl[(wn + j * 16 + ln) * 64 + t + quad * 8];
#pragma unroll
      for (int i = 0; i < 4; i++)
#pragma unroll
        for (int j = 0; j < 4; j++) acc[i][j] = MFMA16(af[i], bfr[j], acc[i][j]);
    }
  }
#pragma unroll
  for (int i = 0; i < 4; i++) {
    int mbase = m0 + wm + i * 16 + quad * 4;
#pragma unroll
    for (int j = 0; j < 4; j++) {
      int n = n0 + wn + j * 16 + ln;
      float bias = bo[n];
#pragma unroll
      for (int r = 0; r < 4; r++) {
        int mm = mbase + r;
        float v = acc[i][j][r] + bias + hid[(size_t)mm * 1024 + n];
        y[(size_t)mm * 1024 + n] = v;
      }
    }
  }
}

// ---------------- K3b: in-place LayerNorm over rows of 1024 ---------------
__global__ __launch_bounds__(256) void k_ln(float* __restrict__ y,
                                            const float* __restrict__ gamma,
                                            const float* __restrict__ beta) {
  int row = blockIdx.x, tid = threadIdx.x;
  float4 v = *(const float4*)&y[(size_t)row * 1024 + tid * 4];
  float s = v.x + v.y + v.z + v.w;
  float sq = v.x * v.x + v.y * v.y + v.z * v.z + v.w * v.w;
#pragma unroll
  for (int off = 32; off > 0; off >>= 1) {
    s += __shfl_xor(s, off);
    sq += __shfl_xor(sq, off);
  }
  __shared__ float red[8];
  int wave = tid >> 6, L = tid & 63;
  if (L == 0) { red[wave] = s; red[4 + wave] = sq; }
  __syncthreads();
  s = red[0] + red[1] + red[2] + red[3];
  sq = red[4] + red[5] + red[6] + red[7];
  float mu = s * (1.f / 1024.f);
  float var = sq * (1.f / 1024.f) - mu * mu;
  float rstd = rsqrtf(var + 1e-5f);
  float4 g = *(const float4*)&gamma[tid * 4];
  float4 be = *(const float4*)&beta[tid * 4];
  float4 o;
  o.x = (v.x - mu) * rstd * g.x + be.x;
  o.y = (v.y - mu) * rstd * g.y + be.y;
  o.z = (v.z - mu) * rstd * g.z + be.z;
  o.w = (v.w - mu) * rstd * g.w + be.w;
  *(float4*)&y[(size_t)row * 1024 + tid * 4] = o;
}

// ---------------- launch --------------------------------------------------
extern "C" void kernel_launch(void* const* d_in, const int* in_sizes, int n_in,
                              void* d_out, int out_size, void* d_ws,
                              size_t ws_size, hipStream_t stream) {
  const float* hid = (const float*)d_in[0];
  const float* mask = (const float*)d_in[1];
  const float* extra = (const float*)d_in[2];
  const float* Wq = (const float*)d_in[3];
  const float* bq = (const float*)d_in[4];
  const float* Wk = (const float*)d_in[5];
  const float* bk = (const float*)d_in[6];
  const float* Wv = (const float*)d_in[7];
  const float* bv = (const float*)d_in[8];
  const float* Wo = (const float*)d_in[9];
  const float* bo = (const float*)d_in[10];
  const float* gamma = (const float*)d_in[11];
  const float* beta = (const float*)d_in[12];
  float* out = (float*)d_out;

  char* ws = (char*)d_ws;
  bf16* hidb  = (bf16*)(ws);                    //  8 MB [4096,1024]
  bf16* wqkvb = (bf16*)(ws + (8ull << 20));     //  6 MB [3072,1024]
  bf16* wob   = (bf16*)(ws + (14ull << 20));    //  2 MB [1024,1024]
  bf16* Qb    = (bf16*)(ws + (16ull << 20));    //  8 MB [32,2048,64]
  bf16* Kb    = (bf16*)(ws + (24ull << 20));    //  8 MB [32,2048,64]
  bf16* Vb    = (bf16*)(ws + (32ull << 20));    //  8 MB [32,64,2048] (transposed)
  bf16* ctx   = (bf16*)(ws + (40ull << 20));    //  8 MB [4096,1024]
  // y lives in d_out (fp32), LN is in-place.

  k_convert<<<8192, 256, 0, stream>>>(hid, Wq, Wk, Wv, Wo, hidb, wqkvb, wob);
  k_qkv_gemm<<<dim3(24, 32), 256, 0, stream>>>(hidb, wqkvb, bq, bk, bv, Qb, Kb, Vb);
  k_attn<<<dim3(32, 32), 256, 0, stream>>>(Qb, Kb, Vb, extra, mask, ctx);
  k_out_gemm<<<dim3(8, 32), 256, 0, stream>>>(ctx, wob, bo, hid, out);
  k_ln<<<4096, 256, 0, stream>>>(out, gamma, beta);
}

// Round 2
// 932.197 us; speedup vs baseline: 1.1081x; 1.1081x over previous
//
#include <hip/hip_runtime.h>
#include <hip/hip_bf16.h>
#include <math.h>

// B=2, S=2048, D=1024, H=16, hd=64. scaling=0.125, LN eps=1e-5.
typedef __bf16 bf16;
typedef __bf16 bf16x4 __attribute__((ext_vector_type(4)));
typedef __bf16 bf16x8 __attribute__((ext_vector_type(8)));
typedef float floatx4 __attribute__((ext_vector_type(4)));

#define MFMA16(a, b, c) __builtin_amdgcn_mfma_f32_16x16x32_bf16(a, b, c, 0, 0, 0)

// async global->LDS, 16B per lane; lds ptr must be wave-uniform (lane i lands
// at lds + i*16). [m97: global_load_lds_dwordx4]
__device__ __forceinline__ void gl_lds16(const bf16* g, bf16* l) {
  __builtin_amdgcn_global_load_lds(
      (const __attribute__((address_space(1))) void*)(g),
      (__attribute__((address_space(3))) void*)(l), 16, 0, 0);
}

// ---------------- K0: fp32 -> bf16 conversions --------------------------
__global__ __launch_bounds__(256) void k_convert(
    const float* __restrict__ hid, const float* __restrict__ wq,
    const float* __restrict__ wk, const float* __restrict__ wv,
    const float* __restrict__ wo,
    bf16* __restrict__ hidb, bf16* __restrict__ wqkvb, bf16* __restrict__ wob) {
  int g = blockIdx.x * 256 + threadIdx.x;
  int idx = g * 4;
  const float* src;
  bf16* dst;
  if (idx < 4194304) {
    src = hid + idx; dst = hidb + idx;
  } else if (idx < 7340032) {
    const float* w = (idx < 5242880) ? wq : (idx < 6291456) ? wk : wv;
    src = w + ((idx - 4194304) & 1048575);
    dst = wqkvb + (idx - 4194304);
  } else {
    src = wo + (idx - 7340032); dst = wob + (idx - 7340032);
  }
  float4 v = *(const float4*)src;
  bf16x4 o;
  o[0] = (bf16)v.x; o[1] = (bf16)v.y; o[2] = (bf16)v.z; o[3] = (bf16)v.w;
  *(bf16x4*)dst = o;
}

// ---------------- K1: fused QKV GEMM (m97-class staging) ------------------
// C[m,n] = sum_k A[m,k]*Bt[n,k];  M=4096, N=3072, K=1024. 128x128 tile.
__global__ __launch_bounds__(256) void k_qkv_gemm(
    const bf16* __restrict__ A, const bf16* __restrict__ Bt,
    const float* __restrict__ bq, const float* __restrict__ bk,
    const float* __restrict__ bv,
    bf16* __restrict__ Qb, bf16* __restrict__ Kb, bf16* __restrict__ Vb) {
  __shared__ __align__(16) bf16 Al[128 * 64];
  __shared__ __align__(16) bf16 Bl[128 * 64];
  int tid = threadIdx.x;
  int wave = tid >> 6, L = tid & 63, quad = L >> 4, ln = L & 15;
  int m0 = blockIdx.y * 128, n0 = blockIdx.x * 128;
  int wm = (wave >> 1) * 64, wn = (wave & 1) * 64;

  floatx4 zz = {0.f, 0.f, 0.f, 0.f};
  floatx4 acc[4][4];
#pragma unroll
  for (int i = 0; i < 4; i++)
#pragma unroll
    for (int j = 0; j < 4; j++) acc[i][j] = zz;

  for (int kk = 0; kk < 1024; kk += 64) {
    __syncthreads();
#pragma unroll
    for (int u = 0; u < 4; u++) {
      int chw = u * 256 + wave * 64;  // wave-uniform chunk base
      int ch = chw + L;
      int r = ch >> 3, c8 = ch & 7;
      gl_lds16(&A[(size_t)(m0 + r) * 1024 + kk + c8 * 8], &Al[chw * 8]);
      gl_lds16(&Bt[(size_t)(n0 + r) * 1024 + kk + c8 * 8], &Bl[chw * 8]);
    }
    __syncthreads();
#pragma unroll
    for (int t = 0; t < 64; t += 32) {
      bf16x8 af[4], bfr[4];
#pragma unroll
      for (int i = 0; i < 4; i++)
        af[i] = *(const bf16x8*)&Al[(wm + i * 16 + ln) * 64 + t + quad * 8];
#pragma unroll
      for (int j = 0; j < 4; j++)
        bfr[j] = *(const bf16x8*)&Bl[(wn + j * 16 + ln) * 64 + t + quad * 8];
#pragma unroll
      for (int i = 0; i < 4; i++)
#pragma unroll
        for (int j = 0; j < 4; j++) acc[i][j] = MFMA16(af[i], bfr[j], acc[i][j]);
    }
  }
#pragma unroll
  for (int i = 0; i < 4; i++) {
    int mbase = m0 + wm + i * 16 + quad * 4;
    int b = mbase >> 11, s0 = mbase & 2047;
#pragma unroll
    for (int j = 0; j < 4; j++) {
      int n = n0 + wn + j * 16 + ln;
      int which = n >> 10, nn = n & 1023;
      float bias = (which == 0) ? bq[nn] : (which == 1) ? bk[nn] : bv[nn];
      int h = nn >> 6, d = nn & 63;
      int bh = b * 16 + h;
      if (which == 2) {
        bf16x4 v4;
#pragma unroll
        for (int r = 0; r < 4; r++) v4[r] = (bf16)(acc[i][j][r] + bias);
        *(bf16x4*)&Vb[(size_t)bh * 131072 + (size_t)d * 2048 + s0] = v4;
      } else {
#pragma unroll
        for (int r = 0; r < 4; r++) {
          float v = acc[i][j][r] + bias;
          if (which == 0)
            Qb[(size_t)bh * 131072 + (s0 + r) * 64 + d] = (bf16)(v * 0.125f);
          else
            Kb[(size_t)bh * 131072 + (s0 + r) * 64 + d] = (bf16)v;
        }
      }
    }
  }
}

// ---------------- K2: flash attention + extra_attn + mask ----------------
// 64 q-rows/block (4 waves x 16), K-tile 64, double-buffered async staging.
__global__ __launch_bounds__(256) void k_attn(
    const bf16* __restrict__ Qb, const bf16* __restrict__ Kb,
    const bf16* __restrict__ Vb, const float* __restrict__ extra,
    const float* __restrict__ mask, bf16* __restrict__ ctx) {
  __shared__ __align__(16) bf16 Kl[2][64 * 64];   // 16 KB
  __shared__ __align__(16) bf16 Vtl[2][64 * 64];  // 16 KB
  __shared__ __align__(16) bf16 Pl[4][16 * 64];   // 8 KB
  int tid = threadIdx.x;
  int wave = tid >> 6, L = tid & 63, quad = L >> 4, ln = L & 15;
  int bh = blockIdx.y, b = bh >> 4, h = bh & 15;
  int qrow = blockIdx.x * 64 + wave * 16;

  bf16x8 qf[2];
  qf[0] = *(const bf16x8*)&Qb[(size_t)bh * 131072 + (qrow + ln) * 64 + quad * 8];
  qf[1] = *(const bf16x8*)&Qb[(size_t)bh * 131072 + (qrow + ln) * 64 + 32 + quad * 8];

  float m_run[4], l_run[4];
  floatx4 zz = {0.f, 0.f, 0.f, 0.f};
  floatx4 Oacc[4];
#pragma unroll
  for (int r = 0; r < 4; r++) { m_run[r] = -INFINITY; l_run[r] = 0.f; }
#pragma unroll
  for (int dd = 0; dd < 4; dd++) Oacc[dd] = zz;

  // per-row extra/mask pointers (lane offset ln baked in)
  const float* eptr[4];
  const float* mptr[4];
#pragma unroll
  for (int r = 0; r < 4; r++) {
    int q = qrow + quad * 4 + r;
    eptr[r] = extra + (size_t)bh * 4194304 + (size_t)q * 2048 + ln;
    mptr[r] = mask + (size_t)b * 4194304 + (size_t)q * 2048 + ln;
  }
  // tile-0 extra prefetch
  float exc[4][4];
#pragma unroll
  for (int kb = 0; kb < 4; kb++)
#pragma unroll
    for (int r = 0; r < 4; r++) exc[kb][r] = eptr[r][kb * 16];

  // tile-0 K/V async stage into buf 0
#pragma unroll
  for (int u = 0; u < 2; u++) {
    int chw = u * 256 + wave * 64;
    int ch = chw + L;
    int row = ch >> 3, c8 = ch & 7;
    gl_lds16(&Kb[(size_t)bh * 131072 + row * 64 + c8 * 8], &Kl[0][chw * 8]);
    gl_lds16(&Vb[(size_t)bh * 131072 + (size_t)row * 2048 + c8 * 8], &Vtl[0][chw * 8]);
  }

  for (int t = 0; t < 32; t++) {
    __syncthreads();  // drains vmcnt: tile-t staging complete; prev reads done
    if (t < 31) {     // stage tile t+1 into the other buffer
      int k0n = (t + 1) * 64;
      bf16* Kn = Kl[(t + 1) & 1];
      bf16* Vn = Vtl[(t + 1) & 1];
#pragma unroll
      for (int u = 0; u < 2; u++) {
        int chw = u * 256 + wave * 64;
        int ch = chw + L;
        int row = ch >> 3, c8 = ch & 7;
        gl_lds16(&Kb[(size_t)bh * 131072 + (k0n + row) * 64 + c8 * 8], &Kn[chw * 8]);
        gl_lds16(&Vb[(size_t)bh * 131072 + (size_t)row * 2048 + k0n + c8 * 8], &Vn[chw * 8]);
      }
    }
    const bf16* Kc = Kl[t & 1];
    const bf16* Vc = Vtl[t & 1];

    // scores: 16q x 64k per wave
    floatx4 sc[4];
#pragma unroll
    for (int kb = 0; kb < 4; kb++) {
      bf16x8 kf0 = *(const bf16x8*)&Kc[(kb * 16 + ln) * 64 + quad * 8];
      bf16x8 kf1 = *(const bf16x8*)&Kc[(kb * 16 + ln) * 64 + 32 + quad * 8];
      floatx4 z = zz;
      z = MFMA16(qf[0], kf0, z);
      z = MFMA16(qf[1], kf1, z);
      sc[kb] = z;
    }
    // prefetch next-tile extra (latency hidden across softmax+PV)
    float en[4][4];
    if (t < 31) {
#pragma unroll
      for (int kb = 0; kb < 4; kb++)
#pragma unroll
        for (int r = 0; r < 4; r++) en[kb][r] = eptr[r][64 + kb * 16];
    }
    // + extra (prefetched) + mask (L3-resident)
#pragma unroll
    for (int kb = 0; kb < 4; kb++)
#pragma unroll
      for (int r = 0; r < 4; r++)
        sc[kb][r] += exc[kb][r] + mptr[r][kb * 16];

    // online softmax over the 16-lane k groups
#pragma unroll
    for (int r = 0; r < 4; r++) {
      float mloc = fmaxf(fmaxf(sc[0][r], sc[1][r]), fmaxf(sc[2][r], sc[3][r]));
      mloc = fmaxf(mloc, __shfl_xor(mloc, 1));
      mloc = fmaxf(mloc, __shfl_xor(mloc, 2));
      mloc = fmaxf(mloc, __shfl_xor(mloc, 4));
      mloc = fmaxf(mloc, __shfl_xor(mloc, 8));
      float m_new = fmaxf(m_run[r], mloc);
      float alpha = __expf(m_run[r] - m_new);
      m_run[r] = m_new;
      float rs = 0.f;
#pragma unroll
      for (int kb = 0; kb < 4; kb++) {
        float p = __expf(sc[kb][r] - m_new);
        sc[kb][r] = p;
        rs += p;
      }
      rs += __shfl_xor(rs, 1);
      rs += __shfl_xor(rs, 2);
      rs += __shfl_xor(rs, 4);
      rs += __shfl_xor(rs, 8);
      l_run[r] = l_run[r] * alpha + rs;
#pragma unroll
      for (int dd = 0; dd < 4; dd++) Oacc[dd][r] *= alpha;
#pragma unroll
      for (int kb = 0; kb < 4; kb++)
        Pl[wave][(quad * 4 + r) * 64 + kb * 16 + ln] = (bf16)sc[kb][r];
    }
    // PV
    bf16x8 pf0 = *(const bf16x8*)&Pl[wave][ln * 64 + quad * 8];
    bf16x8 pf1 = *(const bf16x8*)&Pl[wave][ln * 64 + 32 + quad * 8];
#pragma unroll
    for (int dd = 0; dd < 4; dd++) {
      bf16x8 vf0 = *(const bf16x8*)&Vc[(dd * 16 + ln) * 64 + quad * 8];
      bf16x8 vf1 = *(const bf16x8*)&Vc[(dd * 16 + ln) * 64 + 32 + quad * 8];
      Oacc[dd] = MFMA16(pf0, vf0, Oacc[dd]);
      Oacc[dd] = MFMA16(pf1, vf1, Oacc[dd]);
    }
    // rotate prefetch
    if (t < 31) {
#pragma unroll
      for (int kb = 0; kb < 4; kb++)
#pragma unroll
        for (int r = 0; r < 4; r++) exc[kb][r] = en[kb][r];
#pragma unroll
      for (int r = 0; r < 4; r++) { eptr[r] += 64; mptr[r] += 64; }
    }
  }
  // write context [b, q, h*64+d] bf16
#pragma unroll
  for (int dd = 0; dd < 4; dd++) {
#pragma unroll
    for (int r = 0; r < 4; r++) {
      int q = qrow + quad * 4 + r;
      float v = Oacc[dd][r] / l_run[r];
      ctx[((size_t)(b * 2048 + q)) * 1024 + h * 64 + dd * 16 + ln] = (bf16)v;
    }
  }
}

// ---------------- K3a: output proj + bias + residual ---------------------
// 64(M) x 128(N) tile -> 512 blocks (2/CU). Wave tile 32x64, acc[2][4].
__global__ __launch_bounds__(256) void k_out_gemm(
    const bf16* __restrict__ A, const bf16* __restrict__ Bt,
    const float* __restrict__ bo, const float* __restrict__ hid,
    float* __restrict__ y) {
  __shared__ __align__(16) bf16 Al[64 * 64];
  __shared__ __align__(16) bf16 Bl[128 * 64];
  int tid = threadIdx.x;
  int wave = tid >> 6, L = tid & 63, quad = L >> 4, ln = L & 15;
  int m0 = blockIdx.y * 64, n0 = blockIdx.x * 128;
  int wm = (wave >> 1) * 32, wn = (wave & 1) * 64;

  floatx4 zz = {0.f, 0.f, 0.f, 0.f};
  floatx4 acc[2][4];
#pragma unroll
  for (int i = 0; i < 2; i++)
#pragma unroll
    for (int j = 0; j < 4; j++) acc[i][j] = zz;

  for (int kk = 0; kk < 1024; kk += 64) {
    __syncthreads();
#pragma unroll
    for (int u = 0; u < 2; u++) {
      int chw = u * 256 + wave * 64;
      int ch = chw + L;
      int r = ch >> 3, c8 = ch & 7;
      gl_lds16(&A[(size_t)(m0 + r) * 1024 + kk + c8 * 8], &Al[chw * 8]);
    }
#pragma unroll
    for (int u = 0; u < 4; u++) {
      int chw = u * 256 + wave * 64;
      int ch = chw + L;
      int r = ch >> 3, c8 = ch & 7;
      gl_lds16(&Bt[(size_t)(n0 + r) * 1024 + kk + c8 * 8], &Bl[chw * 8]);
    }
    __syncthreads();
#pragma unroll
    for (int t = 0; t < 64; t += 32) {
      bf16x8 af[2], bfr[4];
#pragma unroll
      for (int i = 0; i < 2; i++)
        af[i] = *(const bf16x8*)&Al[(wm + i * 16 + ln) * 64 + t + quad * 8];
#pragma unroll
      for (int j = 0; j < 4; j++)
        bfr[j] = *(const bf16x8*)&Bl[(wn + j * 16 + ln) * 64 + t + quad * 8];
#pragma unroll
      for (int i = 0; i < 2; i++)
#pragma unroll
        for (int j = 0; j < 4; j++) acc[i][j] = MFMA16(af[i], bfr[j], acc[i][j]);
    }
  }
#pragma unroll
  for (int i = 0; i < 2; i++) {
    int mbase = m0 + wm + i * 16 + quad * 4;
#pragma unroll
    for (int j = 0; j < 4; j++) {
      int n = n0 + wn + j * 16 + ln;
      float bias = bo[n];
#pragma unroll
      for (int r = 0; r < 4; r++) {
        int mm = mbase + r;
        y[(size_t)mm * 1024 + n] = acc[i][j][r] + bias + hid[(size_t)mm * 1024 + n];
      }
    }
  }
}

// ---------------- K3b: in-place LayerNorm over rows of 1024 ---------------
__global__ __launch_bounds__(256) void k_ln(float* __restrict__ y,
                                            const float* __restrict__ gamma,
                                            const float* __restrict__ beta) {
  int row = blockIdx.x, tid = threadIdx.x;
  float4 v = *(const float4*)&y[(size_t)row * 1024 + tid * 4];
  float s = v.x + v.y + v.z + v.w;
  float sq = v.x * v.x + v.y * v.y + v.z * v.z + v.w * v.w;
#pragma unroll
  for (int off = 32; off > 0; off >>= 1) {
    s += __shfl_xor(s, off);
    sq += __shfl_xor(sq, off);
  }
  __shared__ float red[8];
  int wave = tid >> 6, L = tid & 63;
  if (L == 0) { red[wave] = s; red[4 + wave] = sq; }
  __syncthreads();
  s = red[0] + red[1] + red[2] + red[3];
  sq = red[4] + red[5] + red[6] + red[7];
  float mu = s * (1.f / 1024.f);
  float var = sq * (1.f / 1024.f) - mu * mu;
  float rstd = rsqrtf(var + 1e-5f);
  float4 g = *(const float4*)&gamma[tid * 4];
  float4 be = *(const float4*)&beta[tid * 4];
  float4 o;
  o.x = (v.x - mu) * rstd * g.x + be.x;
  o.y = (v.y - mu) * rstd * g.y + be.y;
  o.z = (v.z - mu) * rstd * g.z + be.z;
  o.w = (v.w - mu) * rstd * g.w + be.w;
  *(float4*)&y[(size_t)row * 1024 + tid * 4] = o;
}

// ---------------- launch --------------------------------------------------
extern "C" void kernel_launch(void* const* d_in, const int* in_sizes, int n_in,
                              void* d_out, int out_size, void* d_ws,
                              size_t ws_size, hipStream_t stream) {
  const float* hid = (const float*)d_in[0];
  const float* mask = (const float*)d_in[1];
  const float* extra = (const float*)d_in[2];
  const float* Wq = (const float*)d_in[3];
  const float* bq = (const float*)d_in[4];
  const float* Wk = (const float*)d_in[5];
  const float* bk = (const float*)d_in[6];
  const float* Wv = (const float*)d_in[7];
  const float* bv = (const float*)d_in[8];
  const float* Wo = (const float*)d_in[9];
  const float* bo = (const float*)d_in[10];
  const float* gamma = (const float*)d_in[11];
  const float* beta = (const float*)d_in[12];
  float* out = (float*)d_out;

  char* ws = (char*)d_ws;
  bf16* hidb  = (bf16*)(ws);                    //  8 MB [4096,1024]
  bf16* wqkvb = (bf16*)(ws + (8ull << 20));     //  6 MB [3072,1024]
  bf16* wob   = (bf16*)(ws + (14ull << 20));    //  2 MB [1024,1024]
  bf16* Qb    = (bf16*)(ws + (16ull << 20));    //  8 MB [32,2048,64]
  bf16* Kb    = (bf16*)(ws + (24ull << 20));    //  8 MB [32,2048,64]
  bf16* Vb    = (bf16*)(ws + (32ull << 20));    //  8 MB [32,64,2048] (transposed)
  bf16* ctx   = (bf16*)(ws + (40ull << 20));    //  8 MB [4096,1024]

  k_convert<<<8192, 256, 0, stream>>>(hid, Wq, Wk, Wv, Wo, hidb, wqkvb, wob);
  k_qkv_gemm<<<dim3(24, 32), 256, 0, stream>>>(hidb, wqkvb, bq, bk, bv, Qb, Kb, Vb);
  k_attn<<<dim3(32, 32), 256, 0, stream>>>(Qb, Kb, Vb, extra, mask, ctx);
  k_out_gemm<<<dim3(8, 64), 256, 0, stream>>>(ctx, wob, bo, hid, out);
  k_ln<<<4096, 256, 0, stream>>>(out, gamma, beta);
}

// Round 3
// 924.346 us; speedup vs baseline: 1.1175x; 1.0085x over previous
//
#include <hip/hip_runtime.h>
#include <hip/hip_bf16.h>
#include <math.h>

// B=2, S=2048, D=1024, H=16, hd=64. scaling=0.125, LN eps=1e-5.
typedef __bf16 bf16;
typedef __bf16 bf16x4 __attribute__((ext_vector_type(4)));
typedef __bf16 bf16x8 __attribute__((ext_vector_type(8)));
typedef float floatx4 __attribute__((ext_vector_type(4)));

#define MFMA16(a, b, c) __builtin_amdgcn_mfma_f32_16x16x32_bf16(a, b, c, 0, 0, 0)

// async global->LDS, 16B per lane; lds base must be wave-uniform (lane i lands
// at lds + i*16). [m97: global_load_lds_dwordx4]
__device__ __forceinline__ void gl_lds16(const void* g, void* l) {
  __builtin_amdgcn_global_load_lds(
      (const __attribute__((address_space(1))) void*)(g),
      (__attribute__((address_space(3))) void*)(l), 16, 0, 0);
}

// ---------------- K0: fp32 -> bf16 conversions --------------------------
__global__ __launch_bounds__(256) void k_convert(
    const float* __restrict__ hid, const float* __restrict__ wq,
    const float* __restrict__ wk, const float* __restrict__ wv,
    const float* __restrict__ wo,
    bf16* __restrict__ hidb, bf16* __restrict__ wqkvb, bf16* __restrict__ wob) {
  int g = blockIdx.x * 256 + threadIdx.x;
  int idx = g * 4;
  const float* src;
  bf16* dst;
  if (idx < 4194304) {
    src = hid + idx; dst = hidb + idx;
  } else if (idx < 7340032) {
    const float* w = (idx < 5242880) ? wq : (idx < 6291456) ? wk : wv;
    src = w + ((idx - 4194304) & 1048575);
    dst = wqkvb + (idx - 4194304);
  } else {
    src = wo + (idx - 7340032); dst = wob + (idx - 7340032);
  }
  float4 v = *(const float4*)src;
  bf16x4 o;
  o[0] = (bf16)v.x; o[1] = (bf16)v.y; o[2] = (bf16)v.z; o[3] = (bf16)v.w;
  *(bf16x4*)dst = o;
}

// ---------------- K1: fused QKV GEMM (m97-class staging) ------------------
__global__ __launch_bounds__(256) void k_qkv_gemm(
    const bf16* __restrict__ A, const bf16* __restrict__ Bt,
    const float* __restrict__ bq, const float* __restrict__ bk,
    const float* __restrict__ bv,
    bf16* __restrict__ Qb, bf16* __restrict__ Kb, bf16* __restrict__ Vb) {
  __shared__ __align__(16) bf16 Al[128 * 64];
  __shared__ __align__(16) bf16 Bl[128 * 64];
  int tid = threadIdx.x;
  int wave = tid >> 6, L = tid & 63, quad = L >> 4, ln = L & 15;
  int m0 = blockIdx.y * 128, n0 = blockIdx.x * 128;
  int wm = (wave >> 1) * 64, wn = (wave & 1) * 64;

  floatx4 zz = {0.f, 0.f, 0.f, 0.f};
  floatx4 acc[4][4];
#pragma unroll
  for (int i = 0; i < 4; i++)
#pragma unroll
    for (int j = 0; j < 4; j++) acc[i][j] = zz;

  for (int kk = 0; kk < 1024; kk += 64) {
    __syncthreads();
#pragma unroll
    for (int u = 0; u < 4; u++) {
      int chw = u * 256 + wave * 64;  // wave-uniform chunk base
      int ch = chw + L;
      int r = ch >> 3, c8 = ch & 7;
      gl_lds16(&A[(size_t)(m0 + r) * 1024 + kk + c8 * 8], &Al[chw * 8]);
      gl_lds16(&Bt[(size_t)(n0 + r) * 1024 + kk + c8 * 8], &Bl[chw * 8]);
    }
    __syncthreads();
#pragma unroll
    for (int t = 0; t < 64; t += 32) {
      bf16x8 af[4], bfr[4];
#pragma unroll
      for (int i = 0; i < 4; i++)
        af[i] = *(const bf16x8*)&Al[(wm + i * 16 + ln) * 64 + t + quad * 8];
#pragma unroll
      for (int j = 0; j < 4; j++)
        bfr[j] = *(const bf16x8*)&Bl[(wn + j * 16 + ln) * 64 + t + quad * 8];
#pragma unroll
      for (int i = 0; i < 4; i++)
#pragma unroll
        for (int j = 0; j < 4; j++) acc[i][j] = MFMA16(af[i], bfr[j], acc[i][j]);
    }
  }
#pragma unroll
  for (int i = 0; i < 4; i++) {
    int mbase = m0 + wm + i * 16 + quad * 4;
    int b = mbase >> 11, s0 = mbase & 2047;
#pragma unroll
    for (int j = 0; j < 4; j++) {
      int n = n0 + wn + j * 16 + ln;
      int which = n >> 10, nn = n & 1023;
      float bias = (which == 0) ? bq[nn] : (which == 1) ? bk[nn] : bv[nn];
      int h = nn >> 6, d = nn & 63;
      int bh = b * 16 + h;
      if (which == 2) {
        bf16x4 v4;
#pragma unroll
        for (int r = 0; r < 4; r++) v4[r] = (bf16)(acc[i][j][r] + bias);
        *(bf16x4*)&Vb[(size_t)bh * 131072 + (size_t)d * 2048 + s0] = v4;
      } else {
#pragma unroll
        for (int r = 0; r < 4; r++) {
          float v = acc[i][j][r] + bias;
          if (which == 0)
            Qb[(size_t)bh * 131072 + (s0 + r) * 64 + d] = (bf16)(v * 0.125f);
          else
            Kb[(size_t)bh * 131072 + (s0 + r) * 64 + d] = (bf16)v;
        }
      }
    }
  }
}

// ---------------- K2: flash attention + extra_attn + mask ----------------
// 64 q-rows/block (4 waves x 16), K-tile 64. K,V AND the 64x64 fp32 extra
// tile are all double-buffered async global_load_lds (one tile ahead); mask
// is register-prefetched one tile ahead. LDS 72 KB -> 2 blocks/CU.
__global__ __launch_bounds__(256, 2) void k_attn(
    const bf16* __restrict__ Qb, const bf16* __restrict__ Kb,
    const bf16* __restrict__ Vb, const float* __restrict__ extra,
    const float* __restrict__ mask, bf16* __restrict__ ctx) {
  __shared__ __align__(16) bf16 Kl[2][64 * 64];    // 16 KB
  __shared__ __align__(16) bf16 Vtl[2][64 * 64];   // 16 KB
  __shared__ __align__(16) float El[2][64 * 64];   // 32 KB
  __shared__ __align__(16) bf16 Pl[4][16 * 64];    // 8 KB
  int tid = threadIdx.x;
  int wave = tid >> 6, L = tid & 63, quad = L >> 4, ln = L & 15;
  int bh = blockIdx.y, b = bh >> 4;
  int q0 = blockIdx.x * 64;
  int qrow = q0 + wave * 16;
  int h = bh & 15;

  bf16x8 qf[2];
  qf[0] = *(const bf16x8*)&Qb[(size_t)bh * 131072 + (qrow + ln) * 64 + quad * 8];
  qf[1] = *(const bf16x8*)&Qb[(size_t)bh * 131072 + (qrow + ln) * 64 + 32 + quad * 8];

  float m_run[4], l_run[4];
  floatx4 zz = {0.f, 0.f, 0.f, 0.f};
  floatx4 Oacc[4];
#pragma unroll
  for (int r = 0; r < 4; r++) { m_run[r] = -INFINITY; l_run[r] = 0.f; }
#pragma unroll
  for (int dd = 0; dd < 4; dd++) Oacc[dd] = zz;

  const size_t ebase = (size_t)bh * 4194304;
  // mask pointers per row (lane col offset ln baked in)
  const float* mptr[4];
#pragma unroll
  for (int r = 0; r < 4; r++)
    mptr[r] = mask + (size_t)b * 4194304 + (size_t)(qrow + quad * 4 + r) * 2048 + ln;

  // ---- tile-0 staging: K, V, E into buf 0 ----
#pragma unroll
  for (int u = 0; u < 2; u++) {
    int chw = u * 256 + wave * 64;
    int ch = chw + L;
    int row = ch >> 3, c8 = ch & 7;
    gl_lds16(&Kb[(size_t)bh * 131072 + row * 64 + c8 * 8], &Kl[0][chw * 8]);
    gl_lds16(&Vb[(size_t)bh * 131072 + (size_t)row * 2048 + c8 * 8], &Vtl[0][chw * 8]);
  }
#pragma unroll
  for (int u = 0; u < 4; u++) {
    int chw = u * 256 + wave * 64;
    int ch = chw + L;
    int row = ch >> 4, c = ch & 15;
    gl_lds16(&extra[ebase + (size_t)(q0 + row) * 2048 + c * 4], &El[0][chw * 4]);
  }
  // tile-0 mask prefetch
  float mcur[4][4];
#pragma unroll
  for (int kb = 0; kb < 4; kb++)
#pragma unroll
    for (int r = 0; r < 4; r++) mcur[kb][r] = mptr[r][kb * 16];

  for (int t = 0; t < 32; t++) {
    __syncthreads();  // drains vmcnt: tile-t DMA complete; prev-tile reads done
    if (t < 31) {     // stage tile t+1 (other buffer) — full tile of slack
      int k0n = (t + 1) * 64;
      bf16* Kn = Kl[(t + 1) & 1];
      bf16* Vn = Vtl[(t + 1) & 1];
      float* En = El[(t + 1) & 1];
#pragma unroll
      for (int u = 0; u < 2; u++) {
        int chw = u * 256 + wave * 64;
        int ch = chw + L;
        int row = ch >> 3, c8 = ch & 7;
        gl_lds16(&Kb[(size_t)bh * 131072 + (k0n + row) * 64 + c8 * 8], &Kn[chw * 8]);
        gl_lds16(&Vb[(size_t)bh * 131072 + (size_t)row * 2048 + k0n + c8 * 8], &Vn[chw * 8]);
      }
#pragma unroll
      for (int u = 0; u < 4; u++) {
        int chw = u * 256 + wave * 64;
        int ch = chw + L;
        int row = ch >> 4, c = ch & 15;
        gl_lds16(&extra[ebase + (size_t)(q0 + row) * 2048 + k0n + c * 4], &En[chw * 4]);
      }
    }
    // next-tile mask prefetch (consumed next iteration)
    float mn[4][4];
    if (t < 31) {
#pragma unroll
      for (int kb = 0; kb < 4; kb++)
#pragma unroll
        for (int r = 0; r < 4; r++) mn[kb][r] = mptr[r][64 + kb * 16];
    }
    const bf16* Kc = Kl[t & 1];
    const bf16* Vc = Vtl[t & 1];
    const float* Ec = El[t & 1];

    // scores: 16q x 64k per wave
    floatx4 sc[4];
#pragma unroll
    for (int kb = 0; kb < 4; kb++) {
      bf16x8 kf0 = *(const bf16x8*)&Kc[(kb * 16 + ln) * 64 + quad * 8];
      bf16x8 kf1 = *(const bf16x8*)&Kc[(kb * 16 + ln) * 64 + 32 + quad * 8];
      floatx4 z = zz;
      z = MFMA16(qf[0], kf0, z);
      z = MFMA16(qf[1], kf1, z);
      sc[kb] = z;
    }
    // + extra (LDS, staged) + mask (register-prefetched)
#pragma unroll
    for (int kb = 0; kb < 4; kb++)
#pragma unroll
      for (int r = 0; r < 4; r++)
        sc[kb][r] += Ec[(wave * 16 + quad * 4 + r) * 64 + kb * 16 + ln] + mcur[kb][r];

    // online softmax over the 16-lane k groups
#pragma unroll
    for (int r = 0; r < 4; r++) {
      float mloc = fmaxf(fmaxf(sc[0][r], sc[1][r]), fmaxf(sc[2][r], sc[3][r]));
      mloc = fmaxf(mloc, __shfl_xor(mloc, 1));
      mloc = fmaxf(mloc, __shfl_xor(mloc, 2));
      mloc = fmaxf(mloc, __shfl_xor(mloc, 4));
      mloc = fmaxf(mloc, __shfl_xor(mloc, 8));
      float m_new = fmaxf(m_run[r], mloc);
      float alpha = __expf(m_run[r] - m_new);
      m_run[r] = m_new;
      float rs = 0.f;
#pragma unroll
      for (int kb = 0; kb < 4; kb++) {
        float p = __expf(sc[kb][r] - m_new);
        sc[kb][r] = p;
        rs += p;
      }
      rs += __shfl_xor(rs, 1);
      rs += __shfl_xor(rs, 2);
      rs += __shfl_xor(rs, 4);
      rs += __shfl_xor(rs, 8);
      l_run[r] = l_run[r] * alpha + rs;
#pragma unroll
      for (int dd = 0; dd < 4; dd++) Oacc[dd][r] *= alpha;
#pragma unroll
      for (int kb = 0; kb < 4; kb++)
        Pl[wave][(quad * 4 + r) * 64 + kb * 16 + ln] = (bf16)sc[kb][r];
    }
    // PV
    bf16x8 pf0 = *(const bf16x8*)&Pl[wave][ln * 64 + quad * 8];
    bf16x8 pf1 = *(const bf16x8*)&Pl[wave][ln * 64 + 32 + quad * 8];
#pragma unroll
    for (int dd = 0; dd < 4; dd++) {
      bf16x8 vf0 = *(const bf16x8*)&Vc[(dd * 16 + ln) * 64 + quad * 8];
      bf16x8 vf1 = *(const bf16x8*)&Vc[(dd * 16 + ln) * 64 + 32 + quad * 8];
      Oacc[dd] = MFMA16(pf0, vf0, Oacc[dd]);
      Oacc[dd] = MFMA16(pf1, vf1, Oacc[dd]);
    }
    // rotate mask prefetch
    if (t < 31) {
#pragma unroll
      for (int kb = 0; kb < 4; kb++)
#pragma unroll
        for (int r = 0; r < 4; r++) mcur[kb][r] = mn[kb][r];
#pragma unroll
      for (int r = 0; r < 4; r++) mptr[r] += 64;
    }
  }
  // write context [b, q, h*64+d] bf16
#pragma unroll
  for (int dd = 0; dd < 4; dd++) {
#pragma unroll
    for (int r = 0; r < 4; r++) {
      int q = qrow + quad * 4 + r;
      float v = Oacc[dd][r] / l_run[r];
      ctx[((size_t)(b * 2048 + q)) * 1024 + h * 64 + dd * 16 + ln] = (bf16)v;
    }
  }
}

// ---------------- K3a: output proj + bias + residual ---------------------
__global__ __launch_bounds__(256) void k_out_gemm(
    const bf16* __restrict__ A, const bf16* __restrict__ Bt,
    const float* __restrict__ bo, const float* __restrict__ hid,
    float* __restrict__ y) {
  __shared__ __align__(16) bf16 Al[64 * 64];
  __shared__ __align__(16) bf16 Bl[128 * 64];
  int tid = threadIdx.x;
  int wave = tid >> 6, L = tid & 63, quad = L >> 4, ln = L & 15;
  int m0 = blockIdx.y * 64, n0 = blockIdx.x * 128;
  int wm = (wave >> 1) * 32, wn = (wave & 1) * 64;

  floatx4 zz = {0.f, 0.f, 0.f, 0.f};
  floatx4 acc[2][4];
#pragma unroll
  for (int i = 0; i < 2; i++)
#pragma unroll
    for (int j = 0; j < 4; j++) acc[i][j] = zz;

  for (int kk = 0; kk < 1024; kk += 64) {
    __syncthreads();
#pragma unroll
    for (int u = 0; u < 2; u++) {
      int chw = u * 256 + wave * 64;
      int ch = chw + L;
      int r = ch >> 3, c8 = ch & 7;
      gl_lds16(&A[(size_t)(m0 + r) * 1024 + kk + c8 * 8], &Al[chw * 8]);
    }
#pragma unroll
    for (int u = 0; u < 4; u++) {
      int chw = u * 256 + wave * 64;
      int ch = chw + L;
      int r = ch >> 3, c8 = ch & 7;
      gl_lds16(&Bt[(size_t)(n0 + r) * 1024 + kk + c8 * 8], &Bl[chw * 8]);
    }
    __syncthreads();
#pragma unroll
    for (int t = 0; t < 64; t += 32) {
      bf16x8 af[2], bfr[4];
#pragma unroll
      for (int i = 0; i < 2; i++)
        af[i] = *(const bf16x8*)&Al[(wm + i * 16 + ln) * 64 + t + quad * 8];
#pragma unroll
      for (int j = 0; j < 4; j++)
        bfr[j] = *(const bf16x8*)&Bl[(wn + j * 16 + ln) * 64 + t + quad * 8];
#pragma unroll
      for (int i = 0; i < 2; i++)
#pragma unroll
        for (int j = 0; j < 4; j++) acc[i][j] = MFMA16(af[i], bfr[j], acc[i][j]);
    }
  }
#pragma unroll
  for (int i = 0; i < 2; i++) {
    int mbase = m0 + wm + i * 16 + quad * 4;
#pragma unroll
    for (int j = 0; j < 4; j++) {
      int n = n0 + wn + j * 16 + ln;
      float bias = bo[n];
#pragma unroll
      for (int r = 0; r < 4; r++) {
        int mm = mbase + r;
        y[(size_t)mm * 1024 + n] = acc[i][j][r] + bias + hid[(size_t)mm * 1024 + n];
      }
    }
  }
}

// ---------------- K3b: in-place LayerNorm over rows of 1024 ---------------
__global__ __launch_bounds__(256) void k_ln(float* __restrict__ y,
                                            const float* __restrict__ gamma,
                                            const float* __restrict__ beta) {
  int row = blockIdx.x, tid = threadIdx.x;
  float4 v = *(const float4*)&y[(size_t)row * 1024 + tid * 4];
  float s = v.x + v.y + v.z + v.w;
  float sq = v.x * v.x + v.y * v.y + v.z * v.z + v.w * v.w;
#pragma unroll
  for (int off = 32; off > 0; off >>= 1) {
    s += __shfl_xor(s, off);
    sq += __shfl_xor(sq, off);
  }
  __shared__ float red[8];
  int wave = tid >> 6, L = tid & 63;
  if (L == 0) { red[wave] = s; red[4 + wave] = sq; }
  __syncthreads();
  s = red[0] + red[1] + red[2] + red[3];
  sq = red[4] + red[5] + red[6] + red[7];
  float mu = s * (1.f / 1024.f);
  float var = sq * (1.f / 1024.f) - mu * mu;
  float rstd = rsqrtf(var + 1e-5f);
  float4 g = *(const float4*)&gamma[tid * 4];
  float4 be = *(const float4*)&beta[tid * 4];
  float4 o;
  o.x = (v.x - mu) * rstd * g.x + be.x;
  o.y = (v.y - mu) * rstd * g.y + be.y;
  o.z = (v.z - mu) * rstd * g.z + be.z;
  o.w = (v.w - mu) * rstd * g.w + be.w;
  *(float4*)&y[(size_t)row * 1024 + tid * 4] = o;
}

// ---------------- launch --------------------------------------------------
extern "C" void kernel_launch(void* const* d_in, const int* in_sizes, int n_in,
                              void* d_out, int out_size, void* d_ws,
                              size_t ws_size, hipStream_t stream) {
  const float* hid = (const float*)d_in[0];
  const float* mask = (const float*)d_in[1];
  const float* extra = (const float*)d_in[2];
  const float* Wq = (const float*)d_in[3];
  const float* bq = (const float*)d_in[4];
  const float* Wk = (const float*)d_in[5];
  const float* bk = (const float*)d_in[6];
  const float* Wv = (const float*)d_in[7];
  const float* bv = (const float*)d_in[8];
  const float* Wo = (const float*)d_in[9];
  const float* bo = (const float*)d_in[10];
  const float* gamma = (const float*)d_in[11];
  const float* beta = (const float*)d_in[12];
  float* out = (float*)d_out;

  char* ws = (char*)d_ws;
  bf16* hidb  = (bf16*)(ws);                    //  8 MB [4096,1024]
  bf16* wqkvb = (bf16*)(ws + (8ull << 20));     //  6 MB [3072,1024]
  bf16* wob   = (bf16*)(ws + (14ull << 20));    //  2 MB [1024,1024]
  bf16* Qb    = (bf16*)(ws + (16ull << 20));    //  8 MB [32,2048,64]
  bf16* Kb    = (bf16*)(ws + (24ull << 20));    //  8 MB [32,2048,64]
  bf16* Vb    = (bf16*)(ws + (32ull << 20));    //  8 MB [32,64,2048] (transposed)
  bf16* ctx   = (bf16*)(ws + (40ull << 20));    //  8 MB [4096,1024]

  k_convert<<<8192, 256, 0, stream>>>(hid, Wq, Wk, Wv, Wo, hidb, wqkvb, wob);
  k_qkv_gemm<<<dim3(24, 32), 256, 0, stream>>>(hidb, wqkvb, bq, bk, bv, Qb, Kb, Vb);
  k_attn<<<dim3(32, 32), 256, 0, stream>>>(Qb, Kb, Vb, extra, mask, ctx);
  k_out_gemm<<<dim3(8, 64), 256, 0, stream>>>(ctx, wob, bo, hid, out);
  k_ln<<<4096, 256, 0, stream>>>(out, gamma, beta);
}